// Round 3
// baseline (1172.753 us; speedup 1.0000x reference)
//
#include <hip/hip_runtime.h>

typedef _Float16 half8 __attribute__((ext_vector_type(8)));
typedef float f32x4 __attribute__((ext_vector_type(4)));

constexpr int NB = 2048;        // windows (batch)
constexpr int CDIM = 384;       // channels
constexpr int NH = 12;          // heads
constexpr int MM = NB * 49;     // 100352 rows
constexpr float SCALE = 0.17677669529663687f;  // 1/sqrt(32)

constexpr int XBLK = 37632;     // MM*CDIM/1024
constexpr int WBLK = 2304;      // (1152*384+384*384)/256

constexpr int PROJ_BLOCKS = 3 * (MM / 128);  // 2352 = 8 * 294
constexpr int PROJ_CHUNK  = PROJ_BLOCKS / 8; // 294

// async global->LDS, 16B per lane; lds ptr wave-uniform (HW adds lane*16)
__device__ __forceinline__ void async16(const void* g, void* l) {
    __builtin_amdgcn_global_load_lds((const __attribute__((address_space(1))) void*)g,
                                     (__attribute__((address_space(3))) void*)l, 16, 0, 0);
}

// ---------------- fused prep: convert x, transpose weights, build bias+mask table ----------------
// FT[w][h][k][q] (64x64 f32): rel_bias[h][q][k] + mask[w][q][k]; 0 outside 49x49.

__global__ __launch_bounds__(256) void prep(const float* __restrict__ x,
                                            const float* __restrict__ qkv_w,
                                            const float* __restrict__ proj_w,
                                            const int* __restrict__ rel_index,
                                            const float* __restrict__ rtable,
                                            const float* __restrict__ mask,
                                            _Float16* __restrict__ x_h,
                                            _Float16* __restrict__ qkvT,
                                            _Float16* __restrict__ projT,
                                            float* __restrict__ FT) {
    int bid = blockIdx.x;
    if (bid < XBLK) {
        size_t i = ((size_t)bid * 256 + threadIdx.x) * 4;
        float4 v = *(const float4*)(x + i);
        _Float16 h0 = (_Float16)v.x, h1 = (_Float16)v.y, h2 = (_Float16)v.z, h3 = (_Float16)v.w;
        _Float16* o = x_h + i;
        o[0] = h0; o[1] = h1; o[2] = h2; o[3] = h3;
    } else if (bid < XBLK + WBLK) {
        int i = (bid - XBLK) * 256 + threadIdx.x;
        if (i < 1152 * 384) {
            int n = i / 384, kk = i % 384;
            qkvT[i] = (_Float16)qkv_w[kk * 1152 + n];
        } else {
            int j = i - 1152 * 384;
            int n = j / 384, kk = j % 384;
            projT[j] = (_Float16)proj_w[kk * 384 + n];
        }
    } else {
        int wh = bid - XBLK - WBLK;     // 0..767
        int w = wh / 12, h = wh - w * 12;
        float* dst = FT + (size_t)wh * 4096;
        for (int idx = threadIdx.x; idx < 4096; idx += 256) {
            int k = idx >> 6, q = idx & 63;
            float v = 0.f;
            if (k < 49 && q < 49)
                v = rtable[rel_index[q * 49 + k] * NH + h] + mask[(size_t)w * 2401 + q * 49 + k];
            dst[idx] = v;
        }
    }
}

// ---------------- fused QKV + attention: one block per window ----------------
// 4 waves = 2 groups x 2 waves. Group g owns heads 6g..6g+5 (sequential).
// Within a group, wave p: GEMM computes output cols [16p,16p+16) of Q,K,V (j-split);
// attention handles q-row frags i = 2p..2p+1 (i-split).
// x A-frags read straight from global (L1/L2-hot); no xs staging -> LDS 38.9KB -> 4 blocks/CU.
// Block reorder: 32 consecutive bids share b&63 -> per-XCD L2 caches the FT slice.

__global__ __launch_bounds__(256, 4) void qkv_attn(const _Float16* __restrict__ x_h,
                                                   const _Float16* __restrict__ qkvT,
                                                   const float* __restrict__ qkv_b,
                                                   const float* __restrict__ FT,
                                                   _Float16* __restrict__ ao) {
    __shared__ _Float16 Qs[2][64 * 40];    // per-group Q [q][d], stride 40 (pad 8)
    __shared__ _Float16 Ks[2][64 * 40];    // per-group K [k][d]
    __shared__ _Float16 Vt[2][32 * 72];    // per-group V^T [d][l], l padded to 64
    __shared__ _Float16 Pb[4][16 * 72];    // per-wave P tile

    const int bid = blockIdx.x;
    const int b = (bid & 31) * 64 + (bid >> 5);   // w-locality: b&63 == bid>>5
    const int t = threadIdx.x;
    const int wave = t >> 6, lane = t & 63;
    const int quad = lane >> 4, l16 = lane & 15;
    const int gsel = wave >> 1, p = wave & 1;

    const _Float16* xw = x_h + (size_t)b * 49 * 384;
    _Float16* Qg = Qs[gsel];
    _Float16* Kg = Ks[gsel];
    _Float16* Vg = Vt[gsel];
    _Float16* Pw = Pb[wave];

    for (int hi = 0; hi < 6; hi++) {
        const int h = gsel * 6 + hi;
        const int col = p * 16 + l16;       // this wave's output column (j-split)
        const _Float16* wq = qkvT + (size_t)(h * 32 + col) * 384;
        const _Float16* wk = wq + (size_t)384 * 384;
        const _Float16* wv = wk + (size_t)384 * 384;
        const float bq_b = qkv_b[h * 32 + col];
        const float bk_b = qkv_b[384 + h * 32 + col];
        const float bv_b = qkv_b[768 + h * 32 + col];

        // ---- QKV GEMM for this head: C[64 x 16] per matrix, K=384; A from global
        f32x4 qa[4] = {}, ka[4] = {}, va[4] = {};
#pragma unroll
        for (int kk = 0; kk < 12; kk++) {
            half8 a[4];
#pragma unroll
            for (int i = 0; i < 4; i++)
                a[i] = *(const half8*)(xw + (size_t)(i * 16 + l16) * 384 + kk * 32 + quad * 8);
            half8 bq = *(const half8*)(wq + kk * 32 + quad * 8);
            half8 bk = *(const half8*)(wk + kk * 32 + quad * 8);
            half8 bv = *(const half8*)(wv + kk * 32 + quad * 8);
#pragma unroll
            for (int i = 0; i < 4; i++) {
                qa[i] = __builtin_amdgcn_mfma_f32_16x16x32_f16(a[i], bq, qa[i], 0, 0, 0);
                ka[i] = __builtin_amdgcn_mfma_f32_16x16x32_f16(a[i], bk, ka[i], 0, 0, 0);
                va[i] = __builtin_amdgcn_mfma_f32_16x16x32_f16(a[i], bv, va[i], 0, 0, 0);
            }
        }

        if (hi > 0) __syncthreads();        // prev head's attn reads done before overwrite

        // ---- stage to group LDS (bias, Q-scale; V^T with zeroed rows l>=49)
#pragma unroll
        for (int i = 0; i < 4; i++) {
#pragma unroll
            for (int r = 0; r < 4; r++) {
                int row = i * 16 + quad * 4 + r;
                Qg[row * 40 + col] = (_Float16)((qa[i][r] + bq_b) * SCALE);
                Kg[row * 40 + col] = (_Float16)(ka[i][r] + bk_b);
                Vg[col * 72 + row] = (row < 49) ? (_Float16)(va[i][r] + bv_b) : (_Float16)0.f;
            }
        }
        __syncthreads();

        // ---- attention: wave p handles q-frags i = 2p + i2
        const float* Fb = FT + ((size_t)((b & 63) * 12 + h)) * 4096;
        half8 bkf[4];
#pragma unroll
        for (int j = 0; j < 4; j++)
            bkf[j] = *(const half8*)(&Kg[(j * 16 + l16) * 40 + quad * 8]);
        half8 bvf[2][2];
#pragma unroll
        for (int nt = 0; nt < 2; nt++)
#pragma unroll
            for (int k2 = 0; k2 < 2; k2++)
                bvf[nt][k2] = *(const half8*)(&Vg[(nt * 16 + l16) * 72 + k2 * 32 + quad * 8]);

#pragma unroll
        for (int i2 = 0; i2 < 2; i2++) {
            const int i = p * 2 + i2;
            half8 aq = *(const half8*)(&Qg[(i * 16 + l16) * 40 + quad * 8]);
            f32x4 acc[4];
#pragma unroll
            for (int j = 0; j < 4; j++)
                acc[j] = *(const f32x4*)(Fb + (j * 16 + l16) * 64 + i * 16 + quad * 4);
#pragma unroll
            for (int j = 0; j < 4; j++)
                acc[j] = __builtin_amdgcn_mfma_f32_16x16x32_f16(aq, bkf[j], acc[j], 0, 0, 0);

            if (l16 != 0) {                 // mask k = 48+l16 > 48 (also kills NaN garbage)
#pragma unroll
                for (int r = 0; r < 4; r++) acc[3][r] = -1e30f;
            }

            float rinv[4];
#pragma unroll
            for (int r = 0; r < 4; r++) {
                float m = fmaxf(fmaxf(acc[0][r], acc[1][r]), fmaxf(acc[2][r], acc[3][r]));
                m = fmaxf(m, __shfl_xor(m, 1, 64));
                m = fmaxf(m, __shfl_xor(m, 2, 64));
                m = fmaxf(m, __shfl_xor(m, 4, 64));
                m = fmaxf(m, __shfl_xor(m, 8, 64));
                float sum = 0.f;
#pragma unroll
                for (int j = 0; j < 4; j++) {
                    float e = __expf(acc[j][r] - m);
                    acc[j][r] = e;
                    sum += e;
                }
                sum += __shfl_xor(sum, 1, 64);
                sum += __shfl_xor(sum, 2, 64);
                sum += __shfl_xor(sum, 4, 64);
                sum += __shfl_xor(sum, 8, 64);
                rinv[r] = 1.f / sum;
            }

            // C-layout -> A-layout via per-wave LDS; no barrier needed (same wave)
#pragma unroll
            for (int j = 0; j < 4; j++)
#pragma unroll
                for (int r = 0; r < 4; r++)
                    Pw[(quad * 4 + r) * 72 + j * 16 + l16] = (_Float16)acc[j][r];

            f32x4 oacc[2] = {};
#pragma unroll
            for (int k2 = 0; k2 < 2; k2++) {
                half8 ap = *(const half8*)(&Pw[l16 * 72 + k2 * 32 + quad * 8]);
#pragma unroll
                for (int nt = 0; nt < 2; nt++)
                    oacc[nt] = __builtin_amdgcn_mfma_f32_16x16x32_f16(ap, bvf[nt][k2], oacc[nt], 0, 0, 0);
            }

#pragma unroll
            for (int nt = 0; nt < 2; nt++)
#pragma unroll
                for (int r = 0; r < 4; r++) {
                    int q = i * 16 + quad * 4 + r;
                    if (q < 49)
                        ao[((size_t)b * 49 + q) * CDIM + h * 32 + nt * 16 + l16] =
                            (_Float16)(oacc[nt][r] * rinv[r]);
                }
        }
    }
}

// ---------------- proj GEMM: [100352,384] x [384,384] + bias -> f32 out ----------------

__global__ __launch_bounds__(256) void gemm_proj(const _Float16* __restrict__ A,
                                                 const _Float16* __restrict__ Bt,
                                                 const float* __restrict__ proj_b,
                                                 float* __restrict__ out) {
    __shared__ _Float16 As[128 * 64];
    __shared__ _Float16 Bs[128 * 64];
    const int K = 384;
    const int bid = blockIdx.x;
    const int wid = (bid & 7) * PROJ_CHUNK + (bid >> 3);
    const int tn = wid % 3, tm = wid / 3;
    const int t = threadIdx.x;
    const int wave = t >> 6, lane = t & 63;
    const int wm = (wave & 1) * 64, wn = (wave >> 1) * 64;
    const int quad = lane >> 4, l16 = lane & 15;
    const int rsub = lane >> 3, pp = lane & 7;

    f32x4 acc[4][4] = {};
    const _Float16* Abase = A + (size_t)(tm * 128) * K;
    const _Float16* Bbase = Bt + (size_t)(tn * 128) * K;

    for (int k0 = 0; k0 < K; k0 += 64) {
        __syncthreads();
#pragma unroll
        for (int n = 0; n < 4; n++) {
            int ni = wave * 4 + n;
            int row = ni * 8 + rsub;
            int chunk = pp ^ (row & 7);
            async16(Abase + (size_t)row * K + k0 + chunk * 8, (char*)As + ni * 1024);
            async16(Bbase + (size_t)row * K + k0 + chunk * 8, (char*)Bs + ni * 1024);
        }
        __syncthreads();
#pragma unroll
        for (int ks = 0; ks < 2; ks++) {
            half8 af[4], bfv[4];
#pragma unroll
            for (int i = 0; i < 4; i++)
                af[i] = *(const half8*)(&As[(wm + i * 16 + l16) * 64 + (((ks * 4 + quad) ^ (l16 & 7)) * 8)]);
#pragma unroll
            for (int j = 0; j < 4; j++)
                bfv[j] = *(const half8*)(&Bs[(wn + j * 16 + l16) * 64 + (((ks * 4 + quad) ^ (l16 & 7)) * 8)]);
#pragma unroll
            for (int i = 0; i < 4; i++)
#pragma unroll
                for (int j = 0; j < 4; j++)
                    acc[i][j] = __builtin_amdgcn_mfma_f32_16x16x32_f16(af[i], bfv[j], acc[i][j], 0, 0, 0);
        }
    }

    const int mbase = tm * 128, nbase = tn * 128;
#pragma unroll
    for (int j = 0; j < 4; j++) {
        int n = nbase + wn + j * 16 + l16;
        float bias = proj_b[n];
#pragma unroll
        for (int i = 0; i < 4; i++) {
#pragma unroll
            for (int r = 0; r < 4; r++) {
                int m = mbase + wm + i * 16 + quad * 4 + r;
                out[(size_t)m * CDIM + n] = acc[i][j][r] + bias;
            }
        }
    }
}

// ---------------- launch ----------------

extern "C" void kernel_launch(void* const* d_in, const int* in_sizes, int n_in,
                              void* d_out, int out_size, void* d_ws, size_t ws_size,
                              hipStream_t stream) {
    const float* x        = (const float*)d_in[0];
    const int*   rel_idx  = (const int*)d_in[1];
    const float* amask    = (const float*)d_in[2];
    const float* qkv_w    = (const float*)d_in[3];
    const float* qkv_b    = (const float*)d_in[4];
    const float* rtable   = (const float*)d_in[5];
    const float* proj_w   = (const float*)d_in[6];
    const float* proj_b   = (const float*)d_in[7];
    float* out = (float*)d_out;

    char* w = (char*)d_ws;
    const size_t XB  = (size_t)MM * CDIM * 2;        // 77,070,336
    const size_t XBP = XB + 12288;                   // pad: window 2047 over-reads rows 49..63
    _Float16* x_h    = (_Float16*)w;
    _Float16* wqkvT  = (_Float16*)(w + XBP);
    _Float16* wprojT = (_Float16*)(w + XBP + 884736);
    float*    FT     = (float*)(w + XBP + 884736 + 294912);
    _Float16* ao_h   = (_Float16*)(w + XBP + 884736 + 294912 + 12582912);

    prep<<<XBLK + WBLK + 768, 256, 0, stream>>>(x, qkv_w, proj_w, rel_idx, rtable, amask,
                                                x_h, wqkvT, wprojT, FT);
    qkv_attn<<<NB, 256, 0, stream>>>(x_h, wqkvT, qkv_b, FT, ao_h);
    gemm_proj<<<PROJ_BLOCKS, 256, 0, stream>>>(ao_h, wprojT, proj_b, out);
}

// Round 4
// 708.619 us; speedup vs baseline: 1.6550x; 1.6550x over previous
//
#include <hip/hip_runtime.h>

typedef _Float16 half8 __attribute__((ext_vector_type(8)));
typedef float f32x4 __attribute__((ext_vector_type(4)));

constexpr int NB = 2048;        // windows (batch)
constexpr int CDIM = 384;       // channels
constexpr int NH = 12;          // heads
constexpr int MM = NB * 49;     // 100352 rows = 64 * 1568 exactly
constexpr int NTOT = 1152;      // qkv output cols
constexpr float SCALE = 0.17677669529663687f;  // 1/sqrt(32)

constexpr int XBLK = 37632;     // MM*CDIM/1024
constexpr int WBLK = 2304;      // (1152*384+384*384)/256

constexpr int QKV_BLOCKS = 9 * (MM / 64);    // 14112 = 8 * 1764
constexpr int QKV_CHUNK  = QKV_BLOCKS / 8;   // 1764
constexpr int PROJ_BLOCKS = 3 * (MM / 64);   // 4704 = 8 * 588
constexpr int PROJ_CHUNK  = PROJ_BLOCKS / 8; // 588

// async global->LDS, 16B per lane; lds ptr wave-uniform (HW adds lane*16)
__device__ __forceinline__ void async16(const void* g, void* l) {
    __builtin_amdgcn_global_load_lds((const __attribute__((address_space(1))) void*)g,
                                     (__attribute__((address_space(3))) void*)l, 16, 0, 0);
}

// ---------------- fused prep: convert x, transpose weights, build bias+mask table ----------------
// FT[w][h][k][q] (64x64 f32): rel_bias[h][q][k] + mask[w][q][k]; 0 outside 49x49.

__global__ __launch_bounds__(256) void prep(const float* __restrict__ x,
                                            const float* __restrict__ qkv_w,
                                            const float* __restrict__ proj_w,
                                            const int* __restrict__ rel_index,
                                            const float* __restrict__ rtable,
                                            const float* __restrict__ mask,
                                            _Float16* __restrict__ x_h,
                                            _Float16* __restrict__ qkvT,
                                            _Float16* __restrict__ projT,
                                            float* __restrict__ FT) {
    int bid = blockIdx.x;
    if (bid < XBLK) {
        size_t i = ((size_t)bid * 256 + threadIdx.x) * 4;
        float4 v = *(const float4*)(x + i);
        _Float16 h0 = (_Float16)v.x, h1 = (_Float16)v.y, h2 = (_Float16)v.z, h3 = (_Float16)v.w;
        _Float16* o = x_h + i;
        o[0] = h0; o[1] = h1; o[2] = h2; o[3] = h3;
    } else if (bid < XBLK + WBLK) {
        int i = (bid - XBLK) * 256 + threadIdx.x;
        if (i < 1152 * 384) {
            int n = i / 384, kk = i % 384;
            qkvT[i] = (_Float16)qkv_w[kk * 1152 + n];
        } else {
            int j = i - 1152 * 384;
            int n = j / 384, kk = j % 384;
            projT[j] = (_Float16)proj_w[kk * 384 + n];
        }
    } else {
        int wh = bid - XBLK - WBLK;     // 0..767
        int w = wh / 12, h = wh - w * 12;
        float* dst = FT + (size_t)wh * 4096;
        for (int idx = threadIdx.x; idx < 4096; idx += 256) {
            int k = idx >> 6, q = idx & 63;
            float v = 0.f;
            if (k < 49 && q < 49)
                v = rtable[rel_index[q * 49 + k] * NH + h] + mask[(size_t)w * 2401 + q * 49 + k];
            dst[idx] = v;
        }
    }
}

// ---------------- QKV GEMM, single-barrier full-K blocks ----------------
// BM=64, BN=128, K=384 staged ONCE into LDS (48KB, 16B-chunk XOR swizzle in low 3 bits).
// 8 waves; wave w owns output cols [w*16, w*16+16); B held in 12 half8 registers.
// One barrier between stage and compute (plus epilogue barriers) instead of 12.

__global__ __launch_bounds__(512) void gemm_qkv(const _Float16* __restrict__ A,
                                                const _Float16* __restrict__ Bt,
                                                const float* __restrict__ qkv_b,
                                                _Float16* __restrict__ C) {
    __shared__ union {
        _Float16 As[64 * 384];      // 49152 B
        _Float16 tile[64 * 136];    // 17408 B (epilogue transpose)
    } sm;
    const int K = 384;
    const int bid = blockIdx.x;
    const int wid = (bid & 7) * QKV_CHUNK + (bid >> 3);   // XCD-chunked, bijective
    const int tn = wid % 9, tm = wid / 9;
    const int t = threadIdx.x;
    const int wave = t >> 6, lane = t & 63;
    const int quad = lane >> 4, l16 = lane & 15;

    // ---- stage A rows [tm*64, +64), full K. slot f (16B) = row f/48, pos f%48;
    //      source chunk c = (pos&~7) | ((pos&7) ^ (row&7))  (involution)
    const _Float16* Abase = A + (size_t)(tm * 64) * K;
#pragma unroll
    for (int rnd = 0; rnd < 6; rnd++) {
        int f = rnd * 512 + t;                 // 0..3071
        int row = f / 48, pos = f - row * 48;
        int c = (pos & ~7) | ((pos & 7) ^ (row & 7));
        async16(Abase + (size_t)row * K + c * 8, (char*)sm.As + (rnd * 8192 + wave * 1024));
    }

    // ---- B into registers (overlaps stage latency): lane col = nbase + wave*16 + l16
    const int nbase = tn * 128;
    const int myn = wave * 16 + l16;
    const _Float16* Bb = Bt + (size_t)(nbase + myn) * K + quad * 8;
    half8 breg[12];
#pragma unroll
    for (int kk = 0; kk < 12; kk++) breg[kk] = *(const half8*)(Bb + kk * 32);

    __syncthreads();    // drains stage (vmcnt(0)) + B regs in flight

    // ---- full-K compute: 48 MFMA, A from LDS (conflict-free via XOR swizzle)
    f32x4 acc[4] = {};
#pragma unroll
    for (int kk = 0; kk < 12; kk++) {
#pragma unroll
        for (int i = 0; i < 4; i++) {
            int row = i * 16 + l16;
            int c = kk * 4 + quad;
            int pos = (c & ~7) | ((c & 7) ^ (row & 7));
            half8 a = *(const half8*)(&sm.As[row * 384 + pos * 8]);
            acc[i] = __builtin_amdgcn_mfma_f32_16x16x32_f16(a, breg[kk], acc[i], 0, 0, 0);
        }
    }

    // ---- epilogue: bias (+q-scale) -> f16 LDS transpose tile -> 256B-coalesced stores
    const int mbase = tm * 64;
    const float s = (tn < 3) ? SCALE : 1.f;
    const float bb = qkv_b[nbase + myn];
    __syncthreads();                // all As reads done before overwrite
#pragma unroll
    for (int i = 0; i < 4; i++)
#pragma unroll
        for (int r = 0; r < 4; r++) {
            int m = i * 16 + quad * 4 + r;
            sm.tile[m * 136 + myn] = (_Float16)((acc[i][r] + bb) * s);
        }
    __syncthreads();
#pragma unroll
    for (int g = 0; g < 2; g++) {
        int idx = g * 512 + t;              // 0..1023
        int row = idx >> 4, c8 = idx & 15;
        half8 val = *(const half8*)(&sm.tile[row * 136 + c8 * 8]);
        *(half8*)(C + (size_t)(mbase + row) * NTOT + nbase + c8 * 8) = val;
    }
}

// ---------------- attention: one WAVE per (b,h); no barriers (R0-verified) ----------------

__global__ __launch_bounds__(256) void attn_kernel(const _Float16* __restrict__ C,
                                                   const float* __restrict__ FT,
                                                   _Float16* __restrict__ out) {
    __shared__ _Float16 Vt[4][32 * 72];   // per-wave V^T [d][l], l padded to 64 (zeros)
    __shared__ _Float16 Pb[4][16 * 72];   // per-wave P tile (f16)
    const int t = threadIdx.x;
    const int wave = t >> 6, lane = t & 63, quad = lane >> 4, l16 = lane & 15;
    const int gw = blockIdx.x * 4 + wave;           // global (b,h)
    const int b = gw / 12, h = gw - b * 12;

    const _Float16* qb = C + (size_t)b * 49 * NTOT + h * 32;
    const _Float16* kb = qb + 384;
    const _Float16* vb = qb + 768;
    const float* Fb = FT + ((size_t)((b & 63) * 12 + h)) * 4096;

    _Float16* vt = Vt[wave];
    // zero rows l=48..63 (one b128/wave), then stage V^T rows 0..48
    {
        int d = lane >> 1, seg = lane & 1;
        half8 z = {};
        *(half8*)(&vt[d * 72 + 48 + seg * 8]) = z;
    }
#pragma unroll
    for (int i2 = 0; i2 < 4; i2++) {
        int l = i2 * 16 + (lane >> 2);
        int d0 = (lane & 3) * 8;
        if (l < 49) {
            half8 v8 = *(const half8*)(vb + (size_t)l * NTOT + d0);
#pragma unroll
            for (int e = 0; e < 8; e++)
                vt[(d0 + e) * 72 + l] = v8[e];
        }
    }

    half8 bk[4];
#pragma unroll
    for (int j = 0; j < 4; j++) {
        int krow = j * 16 + l16; if (krow > 48) krow = 48;
        bk[j] = *(const half8*)(kb + (size_t)krow * NTOT + quad * 8);
    }
    half8 bv[2][2];
#pragma unroll
    for (int nt = 0; nt < 2; nt++)
#pragma unroll
        for (int ks = 0; ks < 2; ks++)
            bv[nt][ks] = *(const half8*)(&vt[(nt * 16 + l16) * 72 + ks * 32 + quad * 8]);

    _Float16* Pw = Pb[wave];
#pragma unroll
    for (int i = 0; i < 4; i++) {
        int qrow = i * 16 + l16; if (qrow > 48) qrow = 48;
        half8 aq = *(const half8*)(qb + (size_t)qrow * NTOT + quad * 8);

        f32x4 acc[4];
#pragma unroll
        for (int j = 0; j < 4; j++)
            acc[j] = *(const f32x4*)(Fb + (j * 16 + l16) * 64 + i * 16 + quad * 4);
#pragma unroll
        for (int j = 0; j < 4; j++)
            acc[j] = __builtin_amdgcn_mfma_f32_16x16x32_f16(aq, bk[j], acc[j], 0, 0, 0);

        if (l16 != 0) {                   // mask k = 48+l16 > 48
#pragma unroll
            for (int r = 0; r < 4; r++) acc[3][r] = -1e30f;
        }

        float rinv[4];
#pragma unroll
        for (int r = 0; r < 4; r++) {
            float m = fmaxf(fmaxf(acc[0][r], acc[1][r]), fmaxf(acc[2][r], acc[3][r]));
            m = fmaxf(m, __shfl_xor(m, 1, 64));
            m = fmaxf(m, __shfl_xor(m, 2, 64));
            m = fmaxf(m, __shfl_xor(m, 4, 64));
            m = fmaxf(m, __shfl_xor(m, 8, 64));
            float sum = 0.f;
#pragma unroll
            for (int j = 0; j < 4; j++) {
                float e = __expf(acc[j][r] - m);
                acc[j][r] = e;
                sum += e;
            }
            sum += __shfl_xor(sum, 1, 64);
            sum += __shfl_xor(sum, 2, 64);
            sum += __shfl_xor(sum, 4, 64);
            sum += __shfl_xor(sum, 8, 64);
            rinv[r] = 1.f / sum;
        }

        // C-layout -> A-layout via per-wave LDS (f16, stride 72); no barriers needed
#pragma unroll
        for (int j = 0; j < 4; j++)
#pragma unroll
            for (int r = 0; r < 4; r++)
                Pw[(quad * 4 + r) * 72 + j * 16 + l16] = (_Float16)acc[j][r];

        f32x4 oacc[2] = {};
#pragma unroll
        for (int ks = 0; ks < 2; ks++) {
            half8 ap = *(const half8*)(&Pw[l16 * 72 + ks * 32 + quad * 8]);
#pragma unroll
            for (int nt = 0; nt < 2; nt++)
                oacc[nt] = __builtin_amdgcn_mfma_f32_16x16x32_f16(ap, bv[nt][ks], oacc[nt], 0, 0, 0);
        }

#pragma unroll
        for (int nt = 0; nt < 2; nt++)
#pragma unroll
            for (int r = 0; r < 4; r++) {
                int q = i * 16 + quad * 4 + r;
                if (q < 49)
                    out[((size_t)b * 49 + q) * CDIM + h * 32 + nt * 16 + l16] =
                        (_Float16)(oacc[nt][r] * rinv[r]);
            }
    }
}

// ---------------- proj GEMM, single-barrier full-K blocks: [100352,384]x[384,384]+bias -> f32 ----------------

__global__ __launch_bounds__(512) void gemm_proj(const _Float16* __restrict__ A,
                                                 const _Float16* __restrict__ Bt,
                                                 const float* __restrict__ proj_b,
                                                 float* __restrict__ out) {
    __shared__ union {
        _Float16 As[64 * 384];      // 49152 B
        float tilef[64 * 132];      // 33792 B (epilogue transpose, f32)
    } sm;
    const int K = 384;
    const int bid = blockIdx.x;
    const int wid = (bid & 7) * PROJ_CHUNK + (bid >> 3);
    const int tn = wid % 3, tm = wid / 3;
    const int t = threadIdx.x;
    const int wave = t >> 6, lane = t & 63;
    const int quad = lane >> 4, l16 = lane & 15;

    const _Float16* Abase = A + (size_t)(tm * 64) * K;
#pragma unroll
    for (int rnd = 0; rnd < 6; rnd++) {
        int f = rnd * 512 + t;
        int row = f / 48, pos = f - row * 48;
        int c = (pos & ~7) | ((pos & 7) ^ (row & 7));
        async16(Abase + (size_t)row * K + c * 8, (char*)sm.As + (rnd * 8192 + wave * 1024));
    }

    const int nbase = tn * 128;
    const int myn = wave * 16 + l16;
    const _Float16* Bb = Bt + (size_t)(nbase + myn) * K + quad * 8;
    half8 breg[12];
#pragma unroll
    for (int kk = 0; kk < 12; kk++) breg[kk] = *(const half8*)(Bb + kk * 32);

    __syncthreads();

    f32x4 acc[4] = {};
#pragma unroll
    for (int kk = 0; kk < 12; kk++) {
#pragma unroll
        for (int i = 0; i < 4; i++) {
            int row = i * 16 + l16;
            int c = kk * 4 + quad;
            int pos = (c & ~7) | ((c & 7) ^ (row & 7));
            half8 a = *(const half8*)(&sm.As[row * 384 + pos * 8]);
            acc[i] = __builtin_amdgcn_mfma_f32_16x16x32_f16(a, breg[kk], acc[i], 0, 0, 0);
        }
    }

    const int mbase = tm * 64;
    const float bb = proj_b[nbase + myn];
    __syncthreads();                // all As reads done before overwrite
#pragma unroll
    for (int i = 0; i < 4; i++)
#pragma unroll
        for (int r = 0; r < 4; r++) {
            int m = i * 16 + quad * 4 + r;
            sm.tilef[m * 132 + myn] = acc[i][r] + bb;
        }
    __syncthreads();
#pragma unroll
    for (int g = 0; g < 4; g++) {
        int idx = g * 512 + t;              // 0..2047
        int row = idx >> 5, c4 = idx & 31;
        float4 val = *(const float4*)(&sm.tilef[row * 132 + c4 * 4]);
        *(float4*)(out + (size_t)(mbase + row) * CDIM + nbase + c4 * 4) = val;
    }
}

// ---------------- launch ----------------

extern "C" void kernel_launch(void* const* d_in, const int* in_sizes, int n_in,
                              void* d_out, int out_size, void* d_ws, size_t ws_size,
                              hipStream_t stream) {
    const float* x        = (const float*)d_in[0];
    const int*   rel_idx  = (const int*)d_in[1];
    const float* amask    = (const float*)d_in[2];
    const float* qkv_w    = (const float*)d_in[3];
    const float* qkv_b    = (const float*)d_in[4];
    const float* rtable   = (const float*)d_in[5];
    const float* proj_w   = (const float*)d_in[6];
    const float* proj_b   = (const float*)d_in[7];
    float* out = (float*)d_out;

    char* w = (char*)d_ws;
    const size_t XB = (size_t)MM * CDIM * 2;        // 77,070,336
    const size_t CB = (size_t)MM * NTOT * 2;        // 231,211,008
    _Float16* x_h    = (_Float16*)w;
    _Float16* wqkvT  = (_Float16*)(w + XB);
    _Float16* wprojT = (_Float16*)(w + XB + 884736);
    _Float16* Cbuf   = (_Float16*)(w + XB + 884736 + 294912);
    float*    FT     = (float*)(w + XB + 884736 + 294912 + CB);   // 12,582,912
    _Float16* ao_h   = x_h;   // alias: x_h dead after gemm_qkv

    prep<<<XBLK + WBLK + 768, 256, 0, stream>>>(x, qkv_w, proj_w, rel_idx, rtable, amask,
                                                x_h, wqkvT, wprojT, FT);
    gemm_qkv<<<QKV_BLOCKS, 512, 0, stream>>>(x_h, wqkvT, qkv_b, Cbuf);
    attn_kernel<<<NB * NH / 4, 256, 0, stream>>>(Cbuf, FT, ao_h);
    gemm_proj<<<PROJ_BLOCKS, 512, 0, stream>>>(ao_h, wprojT, proj_b, out);
}

// Round 5
// 654.652 us; speedup vs baseline: 1.7914x; 1.0824x over previous
//
#include <hip/hip_runtime.h>

typedef _Float16 half8 __attribute__((ext_vector_type(8)));
typedef _Float16 half4 __attribute__((ext_vector_type(4)));
typedef float f32x4 __attribute__((ext_vector_type(4)));

constexpr int NB = 2048;        // windows (batch)
constexpr int CDIM = 384;       // channels
constexpr int NH = 12;          // heads
constexpr int MM = NB * 49;     // 100352 rows = 256 * 392
constexpr int NTOT = 1152;      // qkv output cols
constexpr float SCALE = 0.17677669529663687f;  // 1/sqrt(32)

constexpr int XBLK = 37632;     // MM*CDIM/1024
constexpr int WBLK = 2304;      // (1152*384+384*384)/256

constexpr int QKV_BLOCKS = 9 * (MM / 256);   // 3528 = 8 * 441
constexpr int QKV_CHUNK  = QKV_BLOCKS / 8;   // 441
constexpr int PROJ_BLOCKS = 3 * (MM / 256);  // 1176 = 8 * 147
constexpr int PROJ_CHUNK  = PROJ_BLOCKS / 8; // 147

// async global->LDS, 16B per lane; lds ptr wave-uniform (HW adds lane*16)
__device__ __forceinline__ void async16(const void* g, void* l) {
    __builtin_amdgcn_global_load_lds((const __attribute__((address_space(1))) void*)g,
                                     (__attribute__((address_space(3))) void*)l, 16, 0, 0);
}

// ---------------- fused prep: convert x, transpose weights, build bias+mask table ----------------
// FT[w][h][k][q] (64x64 f16): rel_bias[h][q][k] + mask[w][q][k]; 0 outside 49x49.

__global__ __launch_bounds__(256) void prep(const float* __restrict__ x,
                                            const float* __restrict__ qkv_w,
                                            const float* __restrict__ proj_w,
                                            const int* __restrict__ rel_index,
                                            const float* __restrict__ rtable,
                                            const float* __restrict__ mask,
                                            _Float16* __restrict__ x_h,
                                            _Float16* __restrict__ qkvT,
                                            _Float16* __restrict__ projT,
                                            _Float16* __restrict__ FTh) {
    int bid = blockIdx.x;
    if (bid < XBLK) {
        size_t i = ((size_t)bid * 256 + threadIdx.x) * 4;
        float4 v = *(const float4*)(x + i);
        _Float16 h0 = (_Float16)v.x, h1 = (_Float16)v.y, h2 = (_Float16)v.z, h3 = (_Float16)v.w;
        _Float16* o = x_h + i;
        o[0] = h0; o[1] = h1; o[2] = h2; o[3] = h3;
    } else if (bid < XBLK + WBLK) {
        int i = (bid - XBLK) * 256 + threadIdx.x;
        if (i < 1152 * 384) {
            int n = i / 384, kk = i % 384;
            qkvT[i] = (_Float16)qkv_w[kk * 1152 + n];
        } else {
            int j = i - 1152 * 384;
            int n = j / 384, kk = j % 384;
            projT[j] = (_Float16)proj_w[kk * 384 + n];
        }
    } else {
        int wh = bid - XBLK - WBLK;     // 0..767
        int w = wh / 12, h = wh - w * 12;
        _Float16* dst = FTh + (size_t)wh * 4096;
        for (int idx = threadIdx.x; idx < 4096; idx += 256) {
            int k = idx >> 6, q = idx & 63;
            float v = 0.f;
            if (k < 49 && q < 49)
                v = rtable[rel_index[q * 49 + k] * NH + h] + mask[(size_t)w * 2401 + q * 49 + k];
            dst[idx] = (_Float16)v;
        }
    }
}

// ---------------- QKV GEMM: BM=256 x BN=128, K=384, 8 waves ----------------
// R1-verified 2-barrier K-loop structure at doubled M-tile: 192B staged per wave-MFMA
// (was 256B), half the blocks (3528, XCD-chunked). Epilogue: 2 passes x 2 half-tiles.

__global__ __launch_bounds__(512) void gemm_qkv(const _Float16* __restrict__ A,
                                                const _Float16* __restrict__ Bt,
                                                const float* __restrict__ qkv_b,
                                                _Float16* __restrict__ C) {
    __shared__ union {
        struct { _Float16 A[256 * 64]; _Float16 B[128 * 64]; } st;   // 49152 B
        _Float16 tile[2][64 * 136];                                  // 34816 B
    } sm;
    _Float16* As = sm.st.A;
    _Float16* Bs = sm.st.B;

    const int K = 384;
    const int bid = blockIdx.x;
    const int wid = (bid & 7) * QKV_CHUNK + (bid >> 3);   // XCD-chunked, bijective
    const int tn = wid % 9, tm = wid / 9;
    const int t = threadIdx.x;
    const int wave = t >> 6, lane = t & 63;
    const int wm = (wave & 3) * 64, wn = (wave >> 2) * 64;
    const int quad = lane >> 4, l16 = lane & 15;
    const int rsub = lane >> 3, p = lane & 7;

    f32x4 acc[4][4] = {};
    const _Float16* Abase = A + (size_t)(tm * 256) * K;
    const _Float16* Bbase = Bt + (size_t)(tn * 128) * K;

    for (int k0 = 0; k0 < K; k0 += 64) {
        __syncthreads();
#pragma unroll
        for (int n = 0; n < 4; n++) {          // A: 32 1KB-slots, 4 per wave
            int ni = wave * 4 + n;
            int row = ni * 8 + rsub;
            int chunk = p ^ (row & 7);
            async16(Abase + (size_t)row * K + k0 + chunk * 8, (char*)As + ni * 1024);
        }
#pragma unroll
        for (int n = 0; n < 2; n++) {          // B: 16 slots, 2 per wave
            int ni = wave * 2 + n;
            int row = ni * 8 + rsub;
            int chunk = p ^ (row & 7);
            async16(Bbase + (size_t)row * K + k0 + chunk * 8, (char*)Bs + ni * 1024);
        }
        __syncthreads();
#pragma unroll
        for (int ks = 0; ks < 2; ks++) {
            half8 af[4], bfv[4];
#pragma unroll
            for (int i = 0; i < 4; i++)
                af[i] = *(const half8*)(&As[(wm + i * 16 + l16) * 64 + (((ks * 4 + quad) ^ (l16 & 7)) * 8)]);
#pragma unroll
            for (int j = 0; j < 4; j++)
                bfv[j] = *(const half8*)(&Bs[(wn + j * 16 + l16) * 64 + (((ks * 4 + quad) ^ (l16 & 7)) * 8)]);
#pragma unroll
            for (int i = 0; i < 4; i++)
#pragma unroll
                for (int j = 0; j < 4; j++)
                    acc[i][j] = __builtin_amdgcn_mfma_f32_16x16x32_f16(af[i], bfv[j], acc[i][j], 0, 0, 0);
        }
    }

    // ---- epilogue: bias (+q-scale) -> f16 transpose tiles -> 256B-coalesced stores
    const int nbase = tn * 128, mbase = tm * 256;
    const float s = (tn < 3) ? SCALE : 1.f;
    float bj[4];
#pragma unroll
    for (int j = 0; j < 4; j++) bj[j] = qkv_b[nbase + wn + j * 16 + l16];

    for (int pass = 0; pass < 2; pass++) {
        __syncthreads();               // prior LDS reads done before tile overwrite
        int hsel = (wave & 3) - pass * 2;
        if (hsel == 0 || hsel == 1) {  // waves owning row-halves 2*pass, 2*pass+1
            _Float16* tl = sm.tile[hsel];
#pragma unroll
            for (int j = 0; j < 4; j++) {
                int n = wn + j * 16 + l16;
#pragma unroll
                for (int i = 0; i < 4; i++)
#pragma unroll
                    for (int r = 0; r < 4; r++) {
                        int m = i * 16 + quad * 4 + r;
                        tl[m * 136 + n] = (_Float16)((acc[i][j][r] + bj[j]) * s);
                    }
            }
        }
        __syncthreads();
#pragma unroll
        for (int g = 0; g < 4; g++) {
            int idx = g * 512 + t;             // 0..2047
            int half = idx >> 10, rem = idx & 1023;
            int row = rem >> 4, c8 = rem & 15;
            half8 val = *(const half8*)(&sm.tile[half][row * 136 + c8 * 8]);
            *(half8*)(C + (size_t)(mbase + (pass * 2 + half) * 64 + row) * NTOT + nbase + c8 * 8) = val;
        }
    }
}

// ---------------- attention: one WAVE per (b,h); no barriers; FT in f16 ----------------

__global__ __launch_bounds__(256) void attn_kernel(const _Float16* __restrict__ C,
                                                   const _Float16* __restrict__ FTh,
                                                   _Float16* __restrict__ out) {
    __shared__ _Float16 Vt[4][32 * 72];   // per-wave V^T [d][l], l padded to 64 (zeros)
    __shared__ _Float16 Pb[4][16 * 72];   // per-wave P tile (f16)
    const int t = threadIdx.x;
    const int wave = t >> 6, lane = t & 63, quad = lane >> 4, l16 = lane & 15;
    const int gw = blockIdx.x * 4 + wave;           // global (b,h)
    const int b = gw / 12, h = gw - b * 12;

    const _Float16* qb = C + (size_t)b * 49 * NTOT + h * 32;
    const _Float16* kb = qb + 384;
    const _Float16* vb = qb + 768;
    const _Float16* Fb = FTh + ((size_t)((b & 63) * 12 + h)) * 4096;

    _Float16* vt = Vt[wave];
    // zero rows l=48..63 (one b128/wave), then stage V^T rows 0..48
    {
        int d = lane >> 1, seg = lane & 1;
        half8 z = {};
        *(half8*)(&vt[d * 72 + 48 + seg * 8]) = z;
    }
#pragma unroll
    for (int i2 = 0; i2 < 4; i2++) {
        int l = i2 * 16 + (lane >> 2);
        int d0 = (lane & 3) * 8;
        if (l < 49) {
            half8 v8 = *(const half8*)(vb + (size_t)l * NTOT + d0);
#pragma unroll
            for (int e = 0; e < 8; e++)
                vt[(d0 + e) * 72 + l] = v8[e];
        }
    }

    half8 bk[4];
#pragma unroll
    for (int j = 0; j < 4; j++) {
        int krow = j * 16 + l16; if (krow > 48) krow = 48;
        bk[j] = *(const half8*)(kb + (size_t)krow * NTOT + quad * 8);
    }
    half8 bv[2][2];
#pragma unroll
    for (int nt = 0; nt < 2; nt++)
#pragma unroll
        for (int ks = 0; ks < 2; ks++)
            bv[nt][ks] = *(const half8*)(&vt[(nt * 16 + l16) * 72 + ks * 32 + quad * 8]);

    _Float16* Pw = Pb[wave];
#pragma unroll
    for (int i = 0; i < 4; i++) {
        int qrow = i * 16 + l16; if (qrow > 48) qrow = 48;
        half8 aq = *(const half8*)(qb + (size_t)qrow * NTOT + quad * 8);

        f32x4 acc[4] = {};
#pragma unroll
        for (int j = 0; j < 4; j++)
            acc[j] = __builtin_amdgcn_mfma_f32_16x16x32_f16(aq, bk[j], acc[j], 0, 0, 0);
        // add bias+mask (f16 table, f32 accumulate)
#pragma unroll
        for (int j = 0; j < 4; j++) {
            half4 fh = *(const half4*)(Fb + (j * 16 + l16) * 64 + i * 16 + quad * 4);
#pragma unroll
            for (int r = 0; r < 4; r++) acc[j][r] += (float)fh[r];
        }

        if (l16 != 0) {                   // mask k = 48+l16 > 48
#pragma unroll
            for (int r = 0; r < 4; r++) acc[3][r] = -1e30f;
        }

        float rinv[4];
#pragma unroll
        for (int r = 0; r < 4; r++) {
            float m = fmaxf(fmaxf(acc[0][r], acc[1][r]), fmaxf(acc[2][r], acc[3][r]));
            m = fmaxf(m, __shfl_xor(m, 1, 64));
            m = fmaxf(m, __shfl_xor(m, 2, 64));
            m = fmaxf(m, __shfl_xor(m, 4, 64));
            m = fmaxf(m, __shfl_xor(m, 8, 64));
            float sum = 0.f;
#pragma unroll
            for (int j = 0; j < 4; j++) {
                float e = __expf(acc[j][r] - m);
                acc[j][r] = e;
                sum += e;
            }
            sum += __shfl_xor(sum, 1, 64);
            sum += __shfl_xor(sum, 2, 64);
            sum += __shfl_xor(sum, 4, 64);
            sum += __shfl_xor(sum, 8, 64);
            rinv[r] = 1.f / sum;
        }

        // C-layout -> A-layout via per-wave LDS (f16, stride 72); no barriers needed
#pragma unroll
        for (int j = 0; j < 4; j++)
#pragma unroll
            for (int r = 0; r < 4; r++)
                Pw[(quad * 4 + r) * 72 + j * 16 + l16] = (_Float16)acc[j][r];

        f32x4 oacc[2] = {};
#pragma unroll
        for (int ks = 0; ks < 2; ks++) {
            half8 ap = *(const half8*)(&Pw[l16 * 72 + ks * 32 + quad * 8]);
#pragma unroll
            for (int nt = 0; nt < 2; nt++)
                oacc[nt] = __builtin_amdgcn_mfma_f32_16x16x32_f16(ap, bv[nt][ks], oacc[nt], 0, 0, 0);
        }

#pragma unroll
        for (int nt = 0; nt < 2; nt++)
#pragma unroll
            for (int r = 0; r < 4; r++) {
                int q = i * 16 + quad * 4 + r;
                if (q < 49)
                    out[((size_t)b * 49 + q) * CDIM + h * 32 + nt * 16 + l16] =
                        (_Float16)(oacc[nt][r] * rinv[r]);
            }
    }
}

// ---------------- proj GEMM: BM=256 x BN=128, [100352,384]x[384,384]+bias -> f32 ----------------

__global__ __launch_bounds__(512) void gemm_proj(const _Float16* __restrict__ A,
                                                 const _Float16* __restrict__ Bt,
                                                 const float* __restrict__ proj_b,
                                                 float* __restrict__ out) {
    __shared__ _Float16 As[256 * 64];
    __shared__ _Float16 Bs[128 * 64];
    const int K = 384;
    const int bid = blockIdx.x;
    const int wid = (bid & 7) * PROJ_CHUNK + (bid >> 3);
    const int tn = wid % 3, tm = wid / 3;
    const int t = threadIdx.x;
    const int wave = t >> 6, lane = t & 63;
    const int wm = (wave & 3) * 64, wn = (wave >> 2) * 64;
    const int quad = lane >> 4, l16 = lane & 15;
    const int rsub = lane >> 3, p = lane & 7;

    f32x4 acc[4][4] = {};
    const _Float16* Abase = A + (size_t)(tm * 256) * K;
    const _Float16* Bbase = Bt + (size_t)(tn * 128) * K;

    for (int k0 = 0; k0 < K; k0 += 64) {
        __syncthreads();
#pragma unroll
        for (int n = 0; n < 4; n++) {
            int ni = wave * 4 + n;
            int row = ni * 8 + rsub;
            int chunk = p ^ (row & 7);
            async16(Abase + (size_t)row * K + k0 + chunk * 8, (char*)As + ni * 1024);
        }
#pragma unroll
        for (int n = 0; n < 2; n++) {
            int ni = wave * 2 + n;
            int row = ni * 8 + rsub;
            int chunk = p ^ (row & 7);
            async16(Bbase + (size_t)row * K + k0 + chunk * 8, (char*)Bs + ni * 1024);
        }
        __syncthreads();
#pragma unroll
        for (int ks = 0; ks < 2; ks++) {
            half8 af[4], bfv[4];
#pragma unroll
            for (int i = 0; i < 4; i++)
                af[i] = *(const half8*)(&As[(wm + i * 16 + l16) * 64 + (((ks * 4 + quad) ^ (l16 & 7)) * 8)]);
#pragma unroll
            for (int j = 0; j < 4; j++)
                bfv[j] = *(const half8*)(&Bs[(wn + j * 16 + l16) * 64 + (((ks * 4 + quad) ^ (l16 & 7)) * 8)]);
#pragma unroll
            for (int i = 0; i < 4; i++)
#pragma unroll
                for (int j = 0; j < 4; j++)
                    acc[i][j] = __builtin_amdgcn_mfma_f32_16x16x32_f16(af[i], bfv[j], acc[i][j], 0, 0, 0);
        }
    }

    const int mbase = tm * 256, nbase = tn * 128;
#pragma unroll
    for (int j = 0; j < 4; j++) {
        int n = nbase + wn + j * 16 + l16;
        float bias = proj_b[n];
#pragma unroll
        for (int i = 0; i < 4; i++) {
#pragma unroll
            for (int r = 0; r < 4; r++) {
                int m = mbase + wm + i * 16 + quad * 4 + r;
                out[(size_t)m * CDIM + n] = acc[i][j][r] + bias;
            }
        }
    }
}

// ---------------- launch ----------------

extern "C" void kernel_launch(void* const* d_in, const int* in_sizes, int n_in,
                              void* d_out, int out_size, void* d_ws, size_t ws_size,
                              hipStream_t stream) {
    const float* x        = (const float*)d_in[0];
    const int*   rel_idx  = (const int*)d_in[1];
    const float* amask    = (const float*)d_in[2];
    const float* qkv_w    = (const float*)d_in[3];
    const float* qkv_b    = (const float*)d_in[4];
    const float* rtable   = (const float*)d_in[5];
    const float* proj_w   = (const float*)d_in[6];
    const float* proj_b   = (const float*)d_in[7];
    float* out = (float*)d_out;

    char* w = (char*)d_ws;
    const size_t XB = (size_t)MM * CDIM * 2;        // 77,070,336
    const size_t CB = (size_t)MM * NTOT * 2;        // 231,211,008
    _Float16* x_h    = (_Float16*)w;
    _Float16* wqkvT  = (_Float16*)(w + XB);
    _Float16* wprojT = (_Float16*)(w + XB + 884736);
    _Float16* Cbuf   = (_Float16*)(w + XB + 884736 + 294912);
    _Float16* FTh    = (_Float16*)(w + XB + 884736 + 294912 + CB);   // 6,291,456 B
    _Float16* ao_h   = x_h;   // alias: x_h dead after gemm_qkv

    prep<<<XBLK + WBLK + 768, 256, 0, stream>>>(x, qkv_w, proj_w, rel_idx, rtable, amask,
                                                x_h, wqkvT, wprojT, FTh);
    gemm_qkv<<<QKV_BLOCKS, 512, 0, stream>>>(x_h, wqkvT, qkv_b, Cbuf);
    attn_kernel<<<NB * NH / 4, 256, 0, stream>>>(Cbuf, FTh, ao_h);
    gemm_proj<<<PROJ_BLOCKS, 512, 0, stream>>>(ao_h, wprojT, proj_b, out);
}